// Round 4
// baseline (566.812 us; speedup 1.0000x reference)
//
#include <hip/hip_runtime.h>
#include <hip/hip_bf16.h>

#define Bn 32
#define Ln 2048
#define Dn 768
#define Hn 512
#define Mn (Bn*Ln)
#define EPSC 1e-5f

// ws float-offset layout (first 128 KB), then byte regions
#define OFF_S1   0        // [512] masked sum(h)
#define OFF_S2   512      // [512] masked sum(h^2)
#define OFF_CNT  2048     // [32] per-batch counts
#define OFF_PH   2304     // [32*512] pooled relu(BN(h)) sums (atomic)
#define OFF_W1T_BYTES  131072   // bf16 W1^T [512][768] = 786 KB
#define OFF_H_BYTES    1048576  // tiled bf16 h buffer, 64 MB

#define BM 128
#define BN2 128
#define BK 64
#define LDK 72   // padded LDS k-stride (bf16): 144 B -> 2-way banks, 16B-aligned

typedef __attribute__((ext_vector_type(8))) short bf16x8;
typedef __attribute__((ext_vector_type(4))) float f32x4;

static __device__ __forceinline__ unsigned short f2bf(float x) {
  __hip_bfloat16 h = __float2bfloat16(x);
  return *reinterpret_cast<unsigned short*>(&h);
}
static __device__ __forceinline__ unsigned int pk2(float lo, float hi) {
  return (unsigned int)f2bf(lo) | ((unsigned int)f2bf(hi) << 16);
}
static __device__ __forceinline__ float bf2f(unsigned short u) {
  return __uint_as_float(((unsigned int)u) << 16);
}

// blocks 0..31: per-batch valid count. block 32: zero S1,S2,PH.
__global__ __launch_bounds__(256) void pre_kernel(const int* __restrict__ mask,
                                                  float* __restrict__ ws) {
  int blk = blockIdx.x, t = threadIdx.x;
  if (blk < Bn) {
    __shared__ int red[256];
    int s = 0;
#pragma unroll
    for (int i = 0; i < 8; i++) s += mask[blk * Ln + i * 256 + t];
    red[t] = s;
    __syncthreads();
    for (int off = 128; off > 0; off >>= 1) {
      if (t < off) red[t] += red[t + off];
      __syncthreads();
    }
    if (t == 0) ws[OFF_CNT + blk] = (float)red[0];
  } else {
#pragma unroll
    for (int i = 0; i < 4; i++) ws[OFF_S1 + i * 256 + t] = 0.f;
#pragma unroll
    for (int i = 0; i < 64; i++) ws[OFF_PH + i * 256 + t] = 0.f;
  }
}

// W1 [768][512] fp32 -> W1t [512][768] bf16
__global__ __launch_bounds__(256) void transpose_w1(
    const float* __restrict__ W1, unsigned short* __restrict__ W1t) {
  __shared__ float tile[32][33];
  int kx = blockIdx.x * 32;
  int nx = blockIdx.y * 32;
  int tx = threadIdx.x & 31, ty = threadIdx.x >> 5;
#pragma unroll
  for (int i = 0; i < 32; i += 8)
    tile[ty + i][tx] = W1[(size_t)(kx + ty + i) * Hn + nx + tx];
  __syncthreads();
#pragma unroll
  for (int i = 0; i < 32; i += 8)
    W1t[(size_t)(nx + ty + i) * Dn + kx + tx] = f2bf(tile[tx][ty + i]);
}

// GEMM1: h = A @ W1 + b1 via bf16 MFMA, fused masked BN stats.
// Block 128Mx128N, BK=64, 256 thr = 4 waves of 64x64 (2x2).
// LDS ~38 KB -> 3-4 blocks/CU for barrier-overlap (round-2 was 2).
// Hout per 128x128 chunk (chunk = by*4+bx, 16384 elems):
//   w*4096 + (mt*4+nt)*256 + lane*4 + r   (fully-coalesced 512-B stores)
__global__ __launch_bounds__(256, 3) void gemm1_mfma(
    const float* __restrict__ A, const unsigned short* __restrict__ W1t,
    const float* __restrict__ b1, const int* __restrict__ mask,
    unsigned short* __restrict__ Hout,
    float* __restrict__ gsum, float* __restrict__ gsq)
{
  __shared__ unsigned short As[BM * LDK];   // [m][k]
  __shared__ unsigned short Bs[BN2 * LDK];  // [n][k]
  __shared__ float csum[BN2];
  __shared__ float csq[BN2];

  const int t = threadIdx.x;
  const int bx = blockIdx.x;   // N: 0..3
  const int by = blockIdx.y;   // M: 0..511
  const int bm0 = by * BM;
  const int bn0 = bx * BN2;

  const int w = t >> 6;
  const int lane = t & 63;
  const int wm0 = (w >> 1) * 64;
  const int wn0 = (w & 1) * 64;
  const int l15 = lane & 15;
  const int quad = lane >> 4;

  // staging map: thread covers half a row (32 k's) of A and of B
  const int am = t >> 1;           // 0..127
  const int ak = (t & 1) * 32;     // 0 or 32

  const float* Ap = A + (size_t)(bm0 + am) * Dn + ak;
  const unsigned short* Bp = W1t + (size_t)(bn0 + am) * Dn + ak;

  f32x4 acc[4][4];
#pragma unroll
  for (int i = 0; i < 4; i++)
#pragma unroll
    for (int j = 0; j < 4; j++) acc[i][j] = (f32x4){0.f, 0.f, 0.f, 0.f};

  for (int k0 = 0; k0 < Dn; k0 += BK) {
    float4 av[8];
#pragma unroll
    for (int i = 0; i < 8; i++) av[i] = *(const float4*)(Ap + k0 + i * 4);
    uint4 bv[4];
#pragma unroll
    for (int j = 0; j < 4; j++) bv[j] = *(const uint4*)(Bp + k0 + j * 8);
    __syncthreads();
#pragma unroll
    for (int j = 0; j < 4; j++) {
      uint4 pa;
      pa.x = pk2(av[2 * j].x, av[2 * j].y);
      pa.y = pk2(av[2 * j].z, av[2 * j].w);
      pa.z = pk2(av[2 * j + 1].x, av[2 * j + 1].y);
      pa.w = pk2(av[2 * j + 1].z, av[2 * j + 1].w);
      *(uint4*)&As[am * LDK + ak + j * 8] = pa;
      *(uint4*)&Bs[am * LDK + ak + j * 8] = bv[j];
    }
    __syncthreads();
#pragma unroll
    for (int s = 0; s < 2; s++) {
      bf16x8 af[4], bf[4];
#pragma unroll
      for (int mt = 0; mt < 4; mt++)
        af[mt] = *(const bf16x8*)&As[(wm0 + mt * 16 + l15) * LDK + s * 32 + quad * 8];
#pragma unroll
      for (int nt = 0; nt < 4; nt++)
        bf[nt] = *(const bf16x8*)&Bs[(wn0 + nt * 16 + l15) * LDK + s * 32 + quad * 8];
#pragma unroll
      for (int mt = 0; mt < 4; mt++)
#pragma unroll
        for (int nt = 0; nt < 4; nt++)
          acc[mt][nt] = __builtin_amdgcn_mfma_f32_16x16x32_bf16(
              af[mt], bf[nt], acc[mt][nt], 0, 0, 0);
    }
  }

  // ---- epilogue: bias, masked stats, coalesced tiled bf16 store ----
  if (t < BN2) { csum[t] = 0.f; csq[t] = 0.f; }
  __syncthreads();

  float mk[4][4];
#pragma unroll
  for (int mt = 0; mt < 4; mt++) {
    int4 mv = *(const int4*)(mask + bm0 + wm0 + mt * 16 + quad * 4);
    mk[mt][0] = (float)mv.x; mk[mt][1] = (float)mv.y;
    mk[mt][2] = (float)mv.z; mk[mt][3] = (float)mv.w;
  }

  const size_t cbase = ((size_t)(by * 4 + bx)) * 16384 + (size_t)w * 4096;
#pragma unroll
  for (int nt = 0; nt < 4; nt++) {
    const int nl = wn0 + nt * 16 + l15;
    const float bias = b1[bn0 + nl];
    float ps = 0.f, pq = 0.f;
#pragma unroll
    for (int mt = 0; mt < 4; mt++) {
      ushort4 st;
      float v0 = acc[mt][nt][0] + bias;
      float v1 = acc[mt][nt][1] + bias;
      float v2 = acc[mt][nt][2] + bias;
      float v3 = acc[mt][nt][3] + bias;
      ps += v0 * mk[mt][0] + v1 * mk[mt][1] + v2 * mk[mt][2] + v3 * mk[mt][3];
      pq += v0 * v0 * mk[mt][0] + v1 * v1 * mk[mt][1] +
            v2 * v2 * mk[mt][2] + v3 * v3 * mk[mt][3];
      st.x = f2bf(v0); st.y = f2bf(v1); st.z = f2bf(v2); st.w = f2bf(v3);
      *(ushort4*)&Hout[cbase + (size_t)(mt * 4 + nt) * 256 + lane * 4] = st;
    }
    atomicAdd(&csum[nl], ps);
    atomicAdd(&csq[nl], pq);
  }

  __syncthreads();
  if (t < BN2) {
    atomicAdd(&gsum[bn0 + t], csum[t]);
    atomicAdd(&gsq[bn0 + t], csq[t]);
  }
}

// BN(finalize fused) + ReLU + masked pool over the tiled Hout layout.
// One block per 128x128 chunk (2048 blocks). Register accumulation keyed by
// the thread's fixed channel; one LDS combine; one global atomic per channel
// (16 contenders). No separate finalize kernel.
__global__ __launch_bounds__(256) void bnpool_kernel(
    const unsigned short* __restrict__ Hbuf, const int* __restrict__ mask,
    const float* __restrict__ ws, const float* __restrict__ gamma,
    const float* __restrict__ beta, float* __restrict__ PH)
{
  __shared__ float mkf[BM];
  __shared__ float scs[BN2], shs[BN2];
  __shared__ float part[4][64];
  __shared__ float redc[32];
  const int t = threadIdx.x;
  const int chunk = blockIdx.x;        // 0..2047
  const int by = chunk >> 2, bx = chunk & 3;
  const int b = by >> 4;               // 16 M-chunks per batch
  if (t < 32) redc[t] = ws[OFF_CNT + t];
  if (t < BM) mkf[t] = (float)mask[by * BM + t];
  __syncthreads();
  if (t < BN2) {
    float nv = 0.f;
#pragma unroll
    for (int i = 0; i < 32; i++) nv += redc[i];
    nv = fmaxf(nv, 1.f);
    float inv = 1.f / nv;
    int c = bx * BN2 + t;
    float m = ws[OFF_S1 + c] * inv;
    float var = ws[OFF_S2 + c] * inv - m * m;
    float istd = rsqrtf(fmaxf(var, 0.f) + EPSC);
    float sc = istd * gamma[c];
    scs[t] = sc;
    shs[t] = beta[c] - m * sc;
  }
  __syncthreads();

  const int l15 = t & 15, nt = (t >> 4) & 3, w = t >> 6;
  const int wn0 = (w & 1) * 64, wm0 = (w >> 1) * 64;
  const int nl = wn0 + nt * 16 + l15;
  const float scv = scs[nl], shv = shs[nl];
  const unsigned short* base =
      Hbuf + (size_t)chunk * 16384 + (size_t)w * 4096 + nt * 256 + l15 * 4;
  float acc = 0.f;
#pragma unroll
  for (int mt = 0; mt < 4; mt++)
#pragma unroll
    for (int q = 0; q < 4; q++) {
      ushort4 hv = *(const ushort4*)(base + mt * 1024 + q * 64);
      const float* mv = &mkf[wm0 + mt * 16 + q * 4];
      acc += fmaxf(fmaf(bf2f(hv.x), scv, shv), 0.f) * mv[0]
           + fmaxf(fmaf(bf2f(hv.y), scv, shv), 0.f) * mv[1]
           + fmaxf(fmaf(bf2f(hv.z), scv, shv), 0.f) * mv[2]
           + fmaxf(fmaf(bf2f(hv.w), scv, shv), 0.f) * mv[3];
    }
  part[w][nt * 16 + l15] = acc;
  __syncthreads();
  if (t < BN2) {
    int half = t >> 6, cl = t & 63;
    float v = part[half][cl] + part[half + 2][cl];
    atomicAdd(&PH[b * Hn + bx * BN2 + t], v);
  }
}

// out[b][c] = (PH[b]/max(cnt,1)) @ W2[:,c] + b2[c]*(cnt/max(cnt,1))
__global__ __launch_bounds__(128) void final_kernel(
    const float* __restrict__ pooledh, const float* __restrict__ cnt,
    const float* __restrict__ W2, const float* __restrict__ b2,
    float* __restrict__ out)
{
  __shared__ float pr[Hn];
  int b = blockIdx.x >> 2;
  int cc = blockIdx.x & 3;
  int t = threadIdx.x;
  float nb = cnt[b];
  float inv = 1.f / fmaxf(nb, 1.f);
#pragma unroll
  for (int i = 0; i < 4; i++)
    pr[t + i * 128] = pooledh[b * Hn + t + i * 128] * inv;
  __syncthreads();
  int c = cc * 128 + t;
  float a0 = 0.f, a1 = 0.f, a2 = 0.f, a3 = 0.f;
  for (int i = 0; i < Hn; i += 4) {
    a0 = fmaf(pr[i],     W2[(size_t)i * Hn + c],       a0);
    a1 = fmaf(pr[i + 1], W2[(size_t)(i + 1) * Hn + c], a1);
    a2 = fmaf(pr[i + 2], W2[(size_t)(i + 2) * Hn + c], a2);
    a3 = fmaf(pr[i + 3], W2[(size_t)(i + 3) * Hn + c], a3);
  }
  out[b * Hn + c] = (a0 + a1) + (a2 + a3) + b2[c] * (nb * inv);
}

extern "C" void kernel_launch(void* const* d_in, const int* in_sizes, int n_in,
                              void* d_out, int out_size, void* d_ws, size_t ws_size,
                              hipStream_t stream) {
  const float* hidden = (const float*)d_in[0];
  const int*   mask   = (const int*)d_in[1];
  const float* W1     = (const float*)d_in[2];
  const float* b1     = (const float*)d_in[3];
  const float* gamma  = (const float*)d_in[4];
  const float* beta   = (const float*)d_in[5];
  const float* W2     = (const float*)d_in[6];
  const float* b2     = (const float*)d_in[7];
  float* out = (float*)d_out;
  float* ws  = (float*)d_ws;
  unsigned short* W1t  = (unsigned short*)((char*)d_ws + OFF_W1T_BYTES);
  unsigned short* Hbuf = (unsigned short*)((char*)d_ws + OFF_H_BYTES);

  pre_kernel<<<Bn + 1, 256, 0, stream>>>(mask, ws);
  transpose_w1<<<dim3(Dn / 32, Hn / 32), 256, 0, stream>>>(W1, W1t);
  gemm1_mfma<<<dim3(Hn / BN2, Mn / BM), 256, 0, stream>>>(
      hidden, W1t, b1, mask, Hbuf, ws + OFF_S1, ws + OFF_S2);
  bnpool_kernel<<<(Mn / BM) * (Hn / BN2), 256, 0, stream>>>(
      Hbuf, mask, ws, gamma, beta, ws + OFF_PH);
  final_kernel<<<Bn * 4, 128, 0, stream>>>(ws + OFF_PH, ws + OFF_CNT, W2, b2, out);
}

// Round 5
// 390.724 us; speedup vs baseline: 1.4507x; 1.4507x over previous
//
#include <hip/hip_runtime.h>
#include <hip/hip_bf16.h>

#define Bn 32
#define Ln 2048
#define Dn 768
#define Hn 512
#define Mn (Bn*Ln)
#define EPSC 1e-5f

// ws float-offset layout (first 128 KB), then byte regions
#define OFF_S1   0        // [512] masked sum(h)
#define OFF_S2   512      // [512] masked sum(h^2)
#define OFF_CNT  2048     // [32] per-batch counts
#define OFF_PH   2304     // [32*512] pooled relu(BN(h)) sums (atomic)
#define OFF_W1T_BYTES  131072   // bf16 W1^T [512][768] = 786 KB
#define OFF_H_BYTES    1048576  // tiled bf16 h buffer, 64 MB

#define BM 128
#define BN2 256
#define BK 64
#define LDK 72   // padded LDS k-stride (bf16): 144 B -> 2-way banks, 16B-aligned

typedef __attribute__((ext_vector_type(8))) short bf16x8;
typedef __attribute__((ext_vector_type(4))) float f32x4;

static __device__ __forceinline__ unsigned short f2bf(float x) {
  __hip_bfloat16 h = __float2bfloat16(x);
  return *reinterpret_cast<unsigned short*>(&h);
}
static __device__ __forceinline__ float bf2f(unsigned short u) {
  return __uint_as_float(((unsigned int)u) << 16);
}

// blocks 0..31: per-batch valid count. block 32: zero S1,S2,PH.
__global__ __launch_bounds__(256) void pre_kernel(const int* __restrict__ mask,
                                                  float* __restrict__ ws) {
  int blk = blockIdx.x, t = threadIdx.x;
  if (blk < Bn) {
    __shared__ int red[256];
    int s = 0;
#pragma unroll
    for (int i = 0; i < 8; i++) s += mask[blk * Ln + i * 256 + t];
    red[t] = s;
    __syncthreads();
    for (int off = 128; off > 0; off >>= 1) {
      if (t < off) red[t] += red[t + off];
      __syncthreads();
    }
    if (t == 0) ws[OFF_CNT + blk] = (float)red[0];
  } else {
#pragma unroll
    for (int i = 0; i < 4; i++) ws[OFF_S1 + i * 256 + t] = 0.f;
#pragma unroll
    for (int i = 0; i < 64; i++) ws[OFF_PH + i * 256 + t] = 0.f;
  }
}

// W1 [768][512] fp32 -> W1t [512][768] bf16
__global__ __launch_bounds__(256) void transpose_w1(
    const float* __restrict__ W1, unsigned short* __restrict__ W1t) {
  __shared__ float tile[32][33];
  int kx = blockIdx.x * 32;
  int nx = blockIdx.y * 32;
  int tx = threadIdx.x & 31, ty = threadIdx.x >> 5;
#pragma unroll
  for (int i = 0; i < 32; i += 8)
    tile[ty + i][tx] = W1[(size_t)(kx + ty + i) * Hn + nx + tx];
  __syncthreads();
#pragma unroll
  for (int i = 0; i < 32; i += 8)
    W1t[(size_t)(nx + ty + i) * Dn + kx + tx] = f2bf(tile[tx][ty + i]);
}

// GEMM1 (round-2 verbatim, measured 147 us): h = A @ W1 + b1 via bf16 MFMA,
// fused masked BN stats. Block 128Mx256N, BK=64, 512 thr = 8 waves of 64x64.
// Hout layout per 128x256 chunk (chunk = by*2+bx, 32768 elems):
//   w*4096 + (mt*4+nt)*256 + lane*4 + r   (fully-coalesced 512-B stores)
__global__ __launch_bounds__(512, 4) void gemm1_mfma(
    const float* __restrict__ A, const unsigned short* __restrict__ W1t,
    const float* __restrict__ b1, const int* __restrict__ mask,
    unsigned short* __restrict__ Hout,
    float* __restrict__ gsum, float* __restrict__ gsq)
{
  __shared__ unsigned short As[BM * LDK];   // [m][k]
  __shared__ unsigned short Bs[BN2 * LDK];  // [n][k]
  __shared__ float csum[BN2];
  __shared__ float csq[BN2];

  const int t = threadIdx.x;
  const int bx = blockIdx.x;   // N: 0..1
  const int by = blockIdx.y;   // M: 0..511
  const int bm0 = by * BM;
  const int bn0 = bx * BN2;

  const int w = t >> 6;
  const int lane = t & 63;
  const int wm0 = (w >> 2) * 64;
  const int wn0 = (w & 3) * 64;
  const int l15 = lane & 15;
  const int quad = lane >> 4;

  // staging maps
  const int am = t >> 2;           // 0..127
  const int ak = (t & 3) * 16;     // 0/16/32/48
  const int bn = t >> 1;           // 0..255
  const int bk = (t & 1) * 32;     // 0/32

  const float* Ap = A + (size_t)(bm0 + am) * Dn + ak;
  const unsigned short* Bp = W1t + (size_t)(bn0 + bn) * Dn + bk;

  f32x4 acc[4][4];
#pragma unroll
  for (int i = 0; i < 4; i++)
#pragma unroll
    for (int j = 0; j < 4; j++) acc[i][j] = (f32x4){0.f, 0.f, 0.f, 0.f};

  for (int k0 = 0; k0 < Dn; k0 += BK) {
    float4 a0 = *(const float4*)(Ap + k0);
    float4 a1 = *(const float4*)(Ap + k0 + 4);
    float4 a2 = *(const float4*)(Ap + k0 + 8);
    float4 a3 = *(const float4*)(Ap + k0 + 12);
    uint4 bv0 = *(const uint4*)(Bp + k0);
    uint4 bv1 = *(const uint4*)(Bp + k0 + 8);
    uint4 bv2 = *(const uint4*)(Bp + k0 + 16);
    uint4 bv3 = *(const uint4*)(Bp + k0 + 24);
    __syncthreads();
    uint4 p0, p1;
    p0.x = (unsigned int)f2bf(a0.x) | ((unsigned int)f2bf(a0.y) << 16);
    p0.y = (unsigned int)f2bf(a0.z) | ((unsigned int)f2bf(a0.w) << 16);
    p0.z = (unsigned int)f2bf(a1.x) | ((unsigned int)f2bf(a1.y) << 16);
    p0.w = (unsigned int)f2bf(a1.z) | ((unsigned int)f2bf(a1.w) << 16);
    p1.x = (unsigned int)f2bf(a2.x) | ((unsigned int)f2bf(a2.y) << 16);
    p1.y = (unsigned int)f2bf(a2.z) | ((unsigned int)f2bf(a2.w) << 16);
    p1.z = (unsigned int)f2bf(a3.x) | ((unsigned int)f2bf(a3.y) << 16);
    p1.w = (unsigned int)f2bf(a3.z) | ((unsigned int)f2bf(a3.w) << 16);
    *(uint4*)&As[am * LDK + ak] = p0;
    *(uint4*)&As[am * LDK + ak + 8] = p1;
    *(uint4*)&Bs[bn * LDK + bk] = bv0;
    *(uint4*)&Bs[bn * LDK + bk + 8] = bv1;
    *(uint4*)&Bs[bn * LDK + bk + 16] = bv2;
    *(uint4*)&Bs[bn * LDK + bk + 24] = bv3;
    __syncthreads();
#pragma unroll
    for (int s = 0; s < 2; s++) {
      bf16x8 af[4], bf[4];
#pragma unroll
      for (int mt = 0; mt < 4; mt++)
        af[mt] = *(const bf16x8*)&As[(wm0 + mt * 16 + l15) * LDK + s * 32 + quad * 8];
#pragma unroll
      for (int nt = 0; nt < 4; nt++)
        bf[nt] = *(const bf16x8*)&Bs[(wn0 + nt * 16 + l15) * LDK + s * 32 + quad * 8];
#pragma unroll
      for (int mt = 0; mt < 4; mt++)
#pragma unroll
        for (int nt = 0; nt < 4; nt++)
          acc[mt][nt] = __builtin_amdgcn_mfma_f32_16x16x32_bf16(
              af[mt], bf[nt], acc[mt][nt], 0, 0, 0);
    }
  }

  // ---- epilogue: bias, masked stats, coalesced tiled bf16 store ----
  if (t < BN2) { csum[t] = 0.f; csq[t] = 0.f; }
  __syncthreads();

  float mk[4][4];
#pragma unroll
  for (int mt = 0; mt < 4; mt++) {
    int4 mv = *(const int4*)(mask + bm0 + wm0 + mt * 16 + quad * 4);
    mk[mt][0] = (float)mv.x; mk[mt][1] = (float)mv.y;
    mk[mt][2] = (float)mv.z; mk[mt][3] = (float)mv.w;
  }

  const size_t cbase = ((size_t)(by * 2 + bx)) * 32768 + (size_t)w * 4096;
#pragma unroll
  for (int nt = 0; nt < 4; nt++) {
    const int nl = wn0 + nt * 16 + l15;
    const float bias = b1[bn0 + nl];
    float ps = 0.f, pq = 0.f;
#pragma unroll
    for (int mt = 0; mt < 4; mt++) {
      ushort4 st;
      float v0 = acc[mt][nt][0] + bias;
      float v1 = acc[mt][nt][1] + bias;
      float v2 = acc[mt][nt][2] + bias;
      float v3 = acc[mt][nt][3] + bias;
      ps += v0 * mk[mt][0] + v1 * mk[mt][1] + v2 * mk[mt][2] + v3 * mk[mt][3];
      pq += v0 * v0 * mk[mt][0] + v1 * v1 * mk[mt][1] +
            v2 * v2 * mk[mt][2] + v3 * v3 * mk[mt][3];
      st.x = f2bf(v0); st.y = f2bf(v1); st.z = f2bf(v2); st.w = f2bf(v3);
      *(ushort4*)&Hout[cbase + (size_t)(mt * 4 + nt) * 256 + lane * 4] = st;
    }
    atomicAdd(&csum[nl], ps);
    atomicAdd(&csq[nl], pq);
  }

  __syncthreads();
  if (t < BN2) {
    atomicAdd(&gsum[bn0 + t], csum[t]);
    atomicAdd(&gsq[bn0 + t], csq[t]);
  }
}

// BN(finalize fused) + ReLU + masked pool over R2's tiled Hout layout.
// One block per 128x256 chunk (1024 blocks, 256 thr). Thread t owns channel
// nl = t: w&3 = t>>6, nt = (t>>4)&3, l15 = t&15; sweeps wm halves h=0,1
// (w = t>>6 + 4h). Register accumulation, one global atomic per channel
// (16 contenders). No separate finalize kernel, no LDS combine.
__global__ __launch_bounds__(256) void bnpool_kernel(
    const unsigned short* __restrict__ Hbuf, const int* __restrict__ mask,
    const float* __restrict__ ws, const float* __restrict__ gamma,
    const float* __restrict__ beta, float* __restrict__ PH)
{
  __shared__ float mkf[BM];
  __shared__ float redc[32];
  const int t = threadIdx.x;
  const int chunk = blockIdx.x;        // 0..1023
  const int by = chunk >> 1, bx = chunk & 1;
  const int b = chunk >> 5;            // 32 chunks per batch
  if (t < 32) redc[t] = ws[OFF_CNT + t];
  if (t < BM) mkf[t] = (float)mask[by * BM + t];
  __syncthreads();

  float nv = 0.f;
#pragma unroll
  for (int i = 0; i < 32; i++) nv += redc[i];
  nv = fmaxf(nv, 1.f);
  const float inv = 1.f / nv;
  const int c = bx * BN2 + t;
  const float m = ws[OFF_S1 + c] * inv;
  const float var = ws[OFF_S2 + c] * inv - m * m;
  const float istd = rsqrtf(fmaxf(var, 0.f) + EPSC);
  const float scv = istd * gamma[c];
  const float shv = beta[c] - m * scv;

  const int w3 = t >> 6, nt = (t >> 4) & 3, l15 = t & 15;
  float acc = 0.f;
#pragma unroll
  for (int h = 0; h < 2; h++) {
    const int w = w3 + h * 4;          // same wn0 group, wm half h
    const int wm0 = h * 64;
    const unsigned short* base =
        Hbuf + (size_t)chunk * 32768 + (size_t)w * 4096 + nt * 256 + l15 * 4;
#pragma unroll
    for (int mt = 0; mt < 4; mt++)
#pragma unroll
      for (int q = 0; q < 4; q++) {
        ushort4 hv = *(const ushort4*)(base + mt * 1024 + q * 64);
        const float* mv = &mkf[wm0 + mt * 16 + q * 4];
        acc += fmaxf(fmaf(bf2f(hv.x), scv, shv), 0.f) * mv[0]
             + fmaxf(fmaf(bf2f(hv.y), scv, shv), 0.f) * mv[1]
             + fmaxf(fmaf(bf2f(hv.z), scv, shv), 0.f) * mv[2]
             + fmaxf(fmaf(bf2f(hv.w), scv, shv), 0.f) * mv[3];
      }
  }
  atomicAdd(&PH[b * Hn + c], acc);
}

// out[b][c] = (PH[b]/max(cnt,1)) @ W2[:,c] + b2[c]*(cnt/max(cnt,1))
__global__ __launch_bounds__(128) void final_kernel(
    const float* __restrict__ pooledh, const float* __restrict__ cnt,
    const float* __restrict__ W2, const float* __restrict__ b2,
    float* __restrict__ out)
{
  __shared__ float pr[Hn];
  int b = blockIdx.x >> 2;
  int cc = blockIdx.x & 3;
  int t = threadIdx.x;
  float nb = cnt[b];
  float inv = 1.f / fmaxf(nb, 1.f);
#pragma unroll
  for (int i = 0; i < 4; i++)
    pr[t + i * 128] = pooledh[b * Hn + t + i * 128] * inv;
  __syncthreads();
  int c = cc * 128 + t;
  float a0 = 0.f, a1 = 0.f, a2 = 0.f, a3 = 0.f;
  for (int i = 0; i < Hn; i += 4) {
    a0 = fmaf(pr[i],     W2[(size_t)i * Hn + c],       a0);
    a1 = fmaf(pr[i + 1], W2[(size_t)(i + 1) * Hn + c], a1);
    a2 = fmaf(pr[i + 2], W2[(size_t)(i + 2) * Hn + c], a2);
    a3 = fmaf(pr[i + 3], W2[(size_t)(i + 3) * Hn + c], a3);
  }
  out[b * Hn + c] = (a0 + a1) + (a2 + a3) + b2[c] * (nb * inv);
}

extern "C" void kernel_launch(void* const* d_in, const int* in_sizes, int n_in,
                              void* d_out, int out_size, void* d_ws, size_t ws_size,
                              hipStream_t stream) {
  const float* hidden = (const float*)d_in[0];
  const int*   mask   = (const int*)d_in[1];
  const float* W1     = (const float*)d_in[2];
  const float* b1     = (const float*)d_in[3];
  const float* gamma  = (const float*)d_in[4];
  const float* beta   = (const float*)d_in[5];
  const float* W2     = (const float*)d_in[6];
  const float* b2     = (const float*)d_in[7];
  float* out = (float*)d_out;
  float* ws  = (float*)d_ws;
  unsigned short* W1t  = (unsigned short*)((char*)d_ws + OFF_W1T_BYTES);
  unsigned short* Hbuf = (unsigned short*)((char*)d_ws + OFF_H_BYTES);

  pre_kernel<<<Bn + 1, 256, 0, stream>>>(mask, ws);
  transpose_w1<<<dim3(Dn / 32, Hn / 32), 256, 0, stream>>>(W1, W1t);
  gemm1_mfma<<<dim3(Hn / BN2, Mn / BM), 512, 0, stream>>>(
      hidden, W1t, b1, mask, Hbuf, ws + OFF_S1, ws + OFF_S2);
  bnpool_kernel<<<(Mn / BM) * (Hn / BN2), 256, 0, stream>>>(
      Hbuf, mask, ws, gamma, beta, ws + OFF_PH);
  final_kernel<<<Bn * 4, 128, 0, stream>>>(ws + OFF_PH, ws + OFF_CNT, W2, b2, out);
}